// Round 5
// baseline (118.558 us; speedup 1.0000x reference)
//
#include <hip/hip_runtime.h>

#define NN 1024
#define HH 128
#define CC 7

// ---- Kernel A: P = e@mW1[0:H] + mb1 ; Qt[h][i] = (e@mW1[H:2H])[i,h] --------
__global__ __launch_bounds__(128) void precompute_pq(
    const float* __restrict__ e, const float* __restrict__ mW1,
    const float* __restrict__ mb1, float* __restrict__ P, float* __restrict__ Qt)
{
    const int h  = threadIdx.x;
    const int i0 = blockIdx.x * 4;
    __shared__ float eL[4][HH];
    #pragma unroll
    for (int r = 0; r < 4; ++r) eL[r][h] = e[(i0 + r) * HH + h];
    __syncthreads();
    float p[4], q[4];
    const float b = mb1[h];
    #pragma unroll
    for (int r = 0; r < 4; ++r) { p[r] = b; q[r] = 0.f; }
    for (int k = 0; k < HH; ++k) {
        const float w1 = mW1[k * HH + h];
        const float w2 = mW1[(HH + k) * HH + h];
        #pragma unroll
        for (int r = 0; r < 4; ++r) {
            p[r] = fmaf(eL[r][k], w1, p[r]);
            q[r] = fmaf(eL[r][k], w2, q[r]);
        }
    }
    #pragma unroll
    for (int r = 0; r < 4; ++r) P[(i0 + r) * HH + h] = p[r];
    float4 qv = {q[0], q[1], q[2], q[3]};
    *(float4*)(Qt + (size_t)h * NN + i0) = qv;   // transposed store
}

// ---- Kernel B: HSp[jhalf][i][h] = sum_{j in quarter-pair} relu(P+Qt+c@Cw) --
__global__ __launch_bounds__(256) void msg_sum3(
    const float* __restrict__ c, const float* __restrict__ mW1,
    const float* __restrict__ P, const float* __restrict__ Qt,
    float* __restrict__ HSp)
{
    const int bid   = blockIdx.x;
    const int i     = bid >> 1;
    const int jhalf = bid & 1;
    const int t     = threadIdx.x;
    const int wav   = t >> 6;
    const int lane  = t & 63;
    const int hh    = lane + ((wav & 1) << 6);   // 0..127
    const int jq    = wav >> 1;                  // quarter within half: 0/1
    const int jbase = __builtin_amdgcn_readfirstlane(jhalf * 512 + jq * 256);

    float cw[CC];
    #pragma unroll
    for (int k = 0; k < CC; ++k) cw[k] = mW1[(2 * HH + k) * HH + hh];
    const float base = P[i * HH + hh];                     // mb1 folded in
    const float* __restrict__ crow = c + ((size_t)i * NN + jbase) * CC;
    const float* __restrict__ qrow = Qt + (size_t)hh * NN + jbase;  // contiguous in j

    float acc = 0.f;
    float4 q0 = *(const float4*)(qrow);
    float4 q1 = *(const float4*)(qrow + 4);
    for (int jo = 0; jo < 256; jo += 8) {
        float4 qn0, qn1;
        if (jo + 8 < 256) {                                // prefetch next group
            qn0 = *(const float4*)(qrow + jo + 8);
            qn1 = *(const float4*)(qrow + jo + 12);
        }
        const float* __restrict__ cb = crow + (size_t)jo * CC;  // wave-uniform
        const float vq[8] = {q0.x, q0.y, q0.z, q0.w, q1.x, q1.y, q1.z, q1.w};
        #pragma unroll
        for (int u = 0; u < 8; ++u) {
            float v = base + vq[u];
            #pragma unroll
            for (int k = 0; k < CC; ++k)
                v = fmaf(cb[u * CC + k], cw[k], v);
            acc += fmaxf(v, 0.f);
        }
        q0 = qn0; q1 = qn1;
    }

    __shared__ float red[HH];
    if (jq == 1) red[hh] = acc;
    __syncthreads();
    if (jq == 0) HSp[((size_t)jhalf * NN + i) * HH + hh] = acc + red[hh];
}

// ---- Kernel C: agg -> u -> out ---------------------------------------------
__global__ __launch_bounds__(128) void final_mlp(
    const float* __restrict__ e, const float* __restrict__ HSp,
    const float* __restrict__ mW2, const float* __restrict__ mb2,
    const float* __restrict__ uW1, const float* __restrict__ ub1,
    const float* __restrict__ uW2, const float* __restrict__ ub2,
    float* __restrict__ out)
{
    const int h  = threadIdx.x;
    const int i0 = blockIdx.x * 4;
    __shared__ float hsL[4][HH], eL[4][HH], aggL[4][HH], t1L[4][HH];
    #pragma unroll
    for (int r = 0; r < 4; ++r) {
        const size_t ih = (size_t)(i0 + r) * HH + h;
        hsL[r][h] = HSp[ih] + HSp[(size_t)NN * HH + ih];
        eL[r][h]  = e[ih];
    }
    __syncthreads();

    float a[4];
    const float b2 = (float)NN * mb2[h];
    #pragma unroll
    for (int r = 0; r < 4; ++r) a[r] = b2;
    for (int k = 0; k < HH; ++k) {
        const float w = mW2[k * HH + h];
        #pragma unroll
        for (int r = 0; r < 4; ++r) a[r] = fmaf(hsL[r][k], w, a[r]);
    }
    #pragma unroll
    for (int r = 0; r < 4; ++r) aggL[r][h] = a[r];
    __syncthreads();

    float t1[4];
    const float b3 = ub1[h];
    #pragma unroll
    for (int r = 0; r < 4; ++r) t1[r] = b3;
    for (int k = 0; k < HH; ++k) {
        const float w1 = uW1[k * HH + h];
        const float w2 = uW1[(HH + k) * HH + h];
        #pragma unroll
        for (int r = 0; r < 4; ++r) {
            t1[r] = fmaf(aggL[r][k], w1, t1[r]);
            t1[r] = fmaf(eL[r][k],  w2, t1[r]);
        }
    }
    #pragma unroll
    for (int r = 0; r < 4; ++r) t1L[r][h] = fmaxf(t1[r], 0.f);
    __syncthreads();

    float o[4];
    const float b4 = ub2[h];
    #pragma unroll
    for (int r = 0; r < 4; ++r) o[r] = b4;
    for (int k = 0; k < HH; ++k) {
        const float w = uW2[k * HH + h];
        #pragma unroll
        for (int r = 0; r < 4; ++r) o[r] = fmaf(t1L[r][k], w, o[r]);
    }
    #pragma unroll
    for (int r = 0; r < 4; ++r) out[(size_t)(i0 + r) * HH + h] = o[r];
}

extern "C" void kernel_launch(void* const* d_in, const int* in_sizes, int n_in,
                              void* d_out, int out_size, void* d_ws, size_t ws_size,
                              hipStream_t stream) {
    const float* e   = (const float*)d_in[0];
    const float* c   = (const float*)d_in[1];
    const float* mW1 = (const float*)d_in[2];
    const float* mb1 = (const float*)d_in[3];
    const float* mW2 = (const float*)d_in[4];
    const float* mb2 = (const float*)d_in[5];
    const float* uW1 = (const float*)d_in[6];
    const float* ub1 = (const float*)d_in[7];
    const float* uW2 = (const float*)d_in[8];
    const float* ub2 = (const float*)d_in[9];
    float* out = (float*)d_out;

    float* P   = (float*)d_ws;              // N*H
    float* Qt  = P + NN * HH;               // H*N (transposed)
    float* HSp = Qt + NN * HH;              // 2*N*H

    precompute_pq<<<NN / 4, 128, 0, stream>>>(e, mW1, mb1, P, Qt);
    msg_sum3<<<NN * 2, 256, 0, stream>>>(c, mW1, P, Qt, HSp);
    final_mlp<<<NN / 4, 128, 0, stream>>>(e, HSp, mW2, mb2, uW1, ub1, uW2, ub2, out);
}

// Round 6
// 78.962 us; speedup vs baseline: 1.5014x; 1.5014x over previous
//
#include <hip/hip_runtime.h>

#define NN 1024
#define HH 128
#define CC 7

// ---- Kernel A: P = e@mW1[0:H] + mb1 ; Q = e@mW1[H:2H] ----------------------
__global__ __launch_bounds__(128) void precompute_pq(
    const float* __restrict__ e, const float* __restrict__ mW1,
    const float* __restrict__ mb1, float* __restrict__ P, float* __restrict__ Q)
{
    const int h  = threadIdx.x;
    const int i0 = blockIdx.x * 4;
    __shared__ float eL[4][HH];
    #pragma unroll
    for (int r = 0; r < 4; ++r) eL[r][h] = e[(i0 + r) * HH + h];
    __syncthreads();
    float p[4], q[4];
    const float b = mb1[h];
    #pragma unroll
    for (int r = 0; r < 4; ++r) { p[r] = b; q[r] = 0.f; }
    for (int k = 0; k < HH; ++k) {
        const float w1 = mW1[k * HH + h];
        const float w2 = mW1[(HH + k) * HH + h];
        #pragma unroll
        for (int r = 0; r < 4; ++r) {
            p[r] = fmaf(eL[r][k], w1, p[r]);
            q[r] = fmaf(eL[r][k], w2, q[r]);
        }
    }
    #pragma unroll
    for (int r = 0; r < 4; ++r) {
        P[(i0 + r) * HH + h] = p[r];
        Q[(i0 + r) * HH + h] = q[r];
    }
}

// ---- Kernel B: i-pair blocked, 8-deep Q pipeline ---------------------------
// HSp[jq][i][h] = sum_{j in quarter} relu(P[i,h] + Q[j,h] + c[i,j,:]@Cw[:,h])
__global__ __launch_bounds__(256) void msg_sum4(
    const float* __restrict__ c, const float* __restrict__ mW1,
    const float* __restrict__ P, const float* __restrict__ Q,
    float* __restrict__ HSp)
{
    const int bid = blockIdx.x;
    const int i0  = (bid >> 2) * 2;          // 512 i-pairs
    const int jq  = bid & 3;                 // j-quarter (256 j)
    const int t   = threadIdx.x;
    const int hh  = t & 127;
    const int jh  = t >> 7;                  // 0/1: which 128-j half of quarter
    const int jbase = __builtin_amdgcn_readfirstlane(jq * 256 + jh * 128);

    float cw[CC];
    #pragma unroll
    for (int k = 0; k < CC; ++k) cw[k] = mW1[(2 * HH + k) * HH + hh];
    const float base0 = P[(size_t)i0 * HH + hh];        // mb1 folded in
    const float base1 = P[(size_t)(i0 + 1) * HH + hh];
    const float* __restrict__ crow0 = c + ((size_t)i0 * NN + jbase) * CC;
    const float* __restrict__ crow1 = c + ((size_t)(i0 + 1) * NN + jbase) * CC;
    const float* __restrict__ qp    = Q + (size_t)jbase * HH + hh;  // coalesced in hh

    float acc0 = 0.f, acc1 = 0.f;
    float qcur[8], qnxt[8];
    #pragma unroll
    for (int u = 0; u < 8; ++u) qcur[u] = qp[u * HH];
    for (int jo = 0; jo < 128; jo += 8) {
        if (jo + 8 < 128) {                   // prefetch next 8-j group
            const float* __restrict__ qn = qp + (jo + 8) * HH;
            #pragma unroll
            for (int u = 0; u < 8; ++u) qnxt[u] = qn[u * HH];
        }
        const float* __restrict__ cb0 = crow0 + jo * CC;  // wave-uniform -> s_load
        const float* __restrict__ cb1 = crow1 + jo * CC;
        #pragma unroll
        for (int u = 0; u < 8; ++u) {
            float v0 = base0 + qcur[u];
            float v1 = base1 + qcur[u];
            #pragma unroll
            for (int k = 0; k < CC; ++k) {
                v0 = fmaf(cb0[u * CC + k], cw[k], v0);
                v1 = fmaf(cb1[u * CC + k], cw[k], v1);
            }
            acc0 += fmaxf(v0, 0.f);
            acc1 += fmaxf(v1, 0.f);
        }
        #pragma unroll
        for (int u = 0; u < 8; ++u) qcur[u] = qnxt[u];
    }

    __shared__ float red[2][HH];
    if (jh == 1) { red[0][hh] = acc0; red[1][hh] = acc1; }
    __syncthreads();
    if (jh == 0) {
        HSp[((size_t)jq * NN + i0    ) * HH + hh] = acc0 + red[0][hh];
        HSp[((size_t)jq * NN + i0 + 1) * HH + hh] = acc1 + red[1][hh];
    }
}

// ---- Kernel C: agg -> u -> out ---------------------------------------------
__global__ __launch_bounds__(128) void final_mlp(
    const float* __restrict__ e, const float* __restrict__ HSp,
    const float* __restrict__ mW2, const float* __restrict__ mb2,
    const float* __restrict__ uW1, const float* __restrict__ ub1,
    const float* __restrict__ uW2, const float* __restrict__ ub2,
    float* __restrict__ out)
{
    const int h  = threadIdx.x;
    const int i0 = blockIdx.x * 4;
    __shared__ float hsL[4][HH], eL[4][HH], aggL[4][HH], t1L[4][HH];
    #pragma unroll
    for (int r = 0; r < 4; ++r) {
        const size_t ih = (size_t)(i0 + r) * HH + h;
        hsL[r][h] = HSp[ih] + HSp[(size_t)NN * HH + ih]
                  + HSp[2 * (size_t)NN * HH + ih] + HSp[3 * (size_t)NN * HH + ih];
        eL[r][h]  = e[ih];
    }
    __syncthreads();

    float a[4];
    const float b2 = (float)NN * mb2[h];
    #pragma unroll
    for (int r = 0; r < 4; ++r) a[r] = b2;
    for (int k = 0; k < HH; ++k) {
        const float w = mW2[k * HH + h];
        #pragma unroll
        for (int r = 0; r < 4; ++r) a[r] = fmaf(hsL[r][k], w, a[r]);
    }
    #pragma unroll
    for (int r = 0; r < 4; ++r) aggL[r][h] = a[r];
    __syncthreads();

    float t1[4];
    const float b3 = ub1[h];
    #pragma unroll
    for (int r = 0; r < 4; ++r) t1[r] = b3;
    for (int k = 0; k < HH; ++k) {
        const float w1 = uW1[k * HH + h];
        const float w2 = uW1[(HH + k) * HH + h];
        #pragma unroll
        for (int r = 0; r < 4; ++r) {
            t1[r] = fmaf(aggL[r][k], w1, t1[r]);
            t1[r] = fmaf(eL[r][k],  w2, t1[r]);
        }
    }
    #pragma unroll
    for (int r = 0; r < 4; ++r) t1L[r][h] = fmaxf(t1[r], 0.f);
    __syncthreads();

    float o[4];
    const float b4 = ub2[h];
    #pragma unroll
    for (int r = 0; r < 4; ++r) o[r] = b4;
    for (int k = 0; k < HH; ++k) {
        const float w = uW2[k * HH + h];
        #pragma unroll
        for (int r = 0; r < 4; ++r) o[r] = fmaf(t1L[r][k], w, o[r]);
    }
    #pragma unroll
    for (int r = 0; r < 4; ++r) out[(size_t)(i0 + r) * HH + h] = o[r];
}

extern "C" void kernel_launch(void* const* d_in, const int* in_sizes, int n_in,
                              void* d_out, int out_size, void* d_ws, size_t ws_size,
                              hipStream_t stream) {
    const float* e   = (const float*)d_in[0];
    const float* c   = (const float*)d_in[1];
    const float* mW1 = (const float*)d_in[2];
    const float* mb1 = (const float*)d_in[3];
    const float* mW2 = (const float*)d_in[4];
    const float* mb2 = (const float*)d_in[5];
    const float* uW1 = (const float*)d_in[6];
    const float* ub1 = (const float*)d_in[7];
    const float* uW2 = (const float*)d_in[8];
    const float* ub2 = (const float*)d_in[9];
    float* out = (float*)d_out;

    float* P   = (float*)d_ws;              // N*H
    float* Q   = P + NN * HH;               // N*H
    float* HSp = Q + NN * HH;               // 4*N*H partials (3 MB total d_ws)

    precompute_pq<<<NN / 4, 128, 0, stream>>>(e, mW1, mb1, P, Q);
    msg_sum4<<<NN * 2, 256, 0, stream>>>(c, mW1, P, Q, HSp);
    final_mlp<<<NN / 4, 128, 0, stream>>>(e, HSp, mW2, mb2, uW1, ub1, uW2, ub2, out);
}

// Round 7
// 63.755 us; speedup vs baseline: 1.8596x; 1.2385x over previous
//
#include <hip/hip_runtime.h>

#define NN 1024
#define HH 128
#define CC 7
#define BI 8            // i per block
#define BJ 128          // j per block
#define NSLICE (NN/BJ)  // 8 j-slices -> HSp partials
#define QPAD 132        // 128 + 4 pad: keeps 16B align, 2-way-only bank alias

typedef __attribute__((ext_vector_type(8))) short bf16x8;
typedef __attribute__((ext_vector_type(4))) float f32x4;

__device__ inline unsigned short f2bf(float x) {
    union { float f; unsigned u; } v; v.f = x;
    unsigned u = v.u + 0x7FFFu + ((v.u >> 16) & 1);   // RNE
    return (unsigned short)(u >> 16);
}

// ---- Kernel A: P = e@mW1[0:H] + mb1 ; Q = e@mW1[H:2H] ----------------------
__global__ __launch_bounds__(128) void precompute_pq(
    const float* __restrict__ e, const float* __restrict__ mW1,
    const float* __restrict__ mb1, float* __restrict__ P, float* __restrict__ Q)
{
    const int h  = threadIdx.x;
    const int i0 = blockIdx.x * 4;
    __shared__ float eL[4][HH];
    #pragma unroll
    for (int r = 0; r < 4; ++r) eL[r][h] = e[(i0 + r) * HH + h];
    __syncthreads();
    float p[4], q[4];
    const float b = mb1[h];
    #pragma unroll
    for (int r = 0; r < 4; ++r) { p[r] = b; q[r] = 0.f; }
    for (int k = 0; k < HH; ++k) {
        const float w1 = mW1[k * HH + h];
        const float w2 = mW1[(HH + k) * HH + h];
        #pragma unroll
        for (int r = 0; r < 4; ++r) {
            p[r] = fmaf(eL[r][k], w1, p[r]);
            q[r] = fmaf(eL[r][k], w2, q[r]);
        }
    }
    #pragma unroll
    for (int r = 0; r < 4; ++r) {
        P[(i0 + r) * HH + h] = p[r];
        Q[(i0 + r) * HH + h] = q[r];
    }
}

// ---- Kernel B: MFMA message+reduce -----------------------------------------
// HSp[slice][i][h] = sum_{j in slice} relu( (c[i,j,:]@Cw)[h] + P[i,h] + Q[j,h] )
// MFMA 16x16x32 bf16: A = c-chunk [16j x 32k(pad)], B = Cw~ [32k x 16h].
// A-frag: lane l holds A[m=l&15][k=(l>>4)*8+e]  (lanes>=16 all zero, k>=8 pad)
// B-frag: lane l holds B[k=(l>>4)*8+e][n=l&15]
// C/D:    lane l, reg r -> row=(l>>4)*4+r (j), col=l&15 (h)   [m89-verified]
__global__ __launch_bounds__(256, 4) void msg_mfma(
    const float* __restrict__ c, const float* __restrict__ mW1,
    const float* __restrict__ P, const float* __restrict__ Q,
    float* __restrict__ HSp)
{
    const int bid   = blockIdx.x;
    const int islab = bid >> 3;            // 0..127
    const int slice = bid & 7;             // 0..7
    const int i0    = islab * BI;
    const int j0b   = slice * BJ;
    const int t     = threadIdx.x;
    const int w     = t >> 6;              // wave 0..3
    const int l     = t & 63;
    const int g     = l >> 4;              // lane group 0..3
    const int col   = l & 15;
    const int iw0   = i0 + 2 * w;          // this wave's first i

    __shared__ float qch[16 * QPAD];

    // B fragments (Cw zero-padded K 7->32), built once
    bf16x8 bfr[8];
    #pragma unroll
    for (int ht = 0; ht < 8; ++ht) {
        bf16x8 bv = {0,0,0,0,0,0,0,0};
        if (g == 0) {
            #pragma unroll
            for (int k = 0; k < CC; ++k)
                ((short*)&bv)[k] = (short)f2bf(mW1[(2 * HH + k) * HH + 16 * ht + col]);
        }
        bfr[ht] = bv;
    }
    // P values for this wave's 2 i's at this lane's h columns
    float pv[2][8];
    #pragma unroll
    for (int ii = 0; ii < 2; ++ii)
        #pragma unroll
        for (int ht = 0; ht < 8; ++ht)
            pv[ii][ht] = P[(size_t)(iw0 + ii) * HH + 16 * ht + col];

    float acc[2][8];
    #pragma unroll
    for (int ii = 0; ii < 2; ++ii)
        #pragma unroll
        for (int ht = 0; ht < 8; ++ht) acc[ii][ht] = 0.f;

    for (int ch = 0; ch < BJ / 16; ++ch) {
        const int j0 = j0b + ch * 16;
        __syncthreads();                       // protect qch reads of prev chunk
        // stage Q[16j][128h] -> qch[16][QPAD]
        #pragma unroll
        for (int rep = 0; rep < 2; ++rep) {
            const int f4  = t + rep * 256;     // 512 float4s
            const int row = f4 >> 5;
            const int c4  = (f4 & 31) * 4;
            f32x4 qv = *(const f32x4*)(Q + (size_t)(j0 + row) * HH + c4);
            *(f32x4*)(qch + row * QPAD + c4) = qv;
        }
        // A fragments: c rows for 2 i's (lanes 0-15 active)
        bf16x8 afr[2];
        #pragma unroll
        for (int ii = 0; ii < 2; ++ii) {
            bf16x8 av = {0,0,0,0,0,0,0,0};
            if (g == 0) {
                const float* __restrict__ cp =
                    c + ((size_t)(iw0 + ii) * NN + j0 + col) * CC;
                #pragma unroll
                for (int k = 0; k < CC; ++k)
                    ((short*)&av)[k] = (short)f2bf(cp[k]);
            }
            afr[ii] = av;
        }
        __syncthreads();                       // qch ready
        #pragma unroll
        for (int ht = 0; ht < 8; ++ht) {
            f32x4 d0 = {0.f, 0.f, 0.f, 0.f};
            f32x4 d1 = {0.f, 0.f, 0.f, 0.f};
            d0 = __builtin_amdgcn_mfma_f32_16x16x32_bf16(afr[0], bfr[ht], d0, 0, 0, 0);
            d1 = __builtin_amdgcn_mfma_f32_16x16x32_bf16(afr[1], bfr[ht], d1, 0, 0, 0);
            #pragma unroll
            for (int r = 0; r < 4; ++r) {
                const float q  = qch[(g * 4 + r) * QPAD + 16 * ht + col];
                const float v0 = d0[r] + (pv[0][ht] + q);
                const float v1 = d1[r] + (pv[1][ht] + q);
                acc[0][ht] += fmaxf(v0, 0.f);
                acc[1][ht] += fmaxf(v1, 0.f);
            }
        }
    }
    // reduce partial j-sums across the 4 lane groups
    #pragma unroll
    for (int ii = 0; ii < 2; ++ii)
        #pragma unroll
        for (int ht = 0; ht < 8; ++ht) {
            float a = acc[ii][ht];
            a += __shfl_xor(a, 16, 64);
            a += __shfl_xor(a, 32, 64);
            acc[ii][ht] = a;
        }
    // store: group g writes ht = g and g+4
    #pragma unroll
    for (int ii = 0; ii < 2; ++ii)
        #pragma unroll
        for (int s = 0; s < 2; ++s) {
            const int ht = g + 4 * s;
            HSp[((size_t)slice * NN + iw0 + ii) * HH + 16 * ht + col] = acc[ii][ht];
        }
}

// ---- Kernel C: agg -> u -> out ---------------------------------------------
__global__ __launch_bounds__(128) void final_mlp(
    const float* __restrict__ e, const float* __restrict__ HSp,
    const float* __restrict__ mW2, const float* __restrict__ mb2,
    const float* __restrict__ uW1, const float* __restrict__ ub1,
    const float* __restrict__ uW2, const float* __restrict__ ub2,
    float* __restrict__ out)
{
    const int h  = threadIdx.x;
    const int i0 = blockIdx.x * 4;
    __shared__ float hsL[4][HH], eL[4][HH], aggL[4][HH], t1L[4][HH];
    #pragma unroll
    for (int r = 0; r < 4; ++r) {
        const size_t ih = (size_t)(i0 + r) * HH + h;
        float s = 0.f;
        #pragma unroll
        for (int sl = 0; sl < NSLICE; ++sl)
            s += HSp[(size_t)sl * NN * HH + ih];
        hsL[r][h] = s;
        eL[r][h]  = e[ih];
    }
    __syncthreads();

    float a[4];
    const float b2 = (float)NN * mb2[h];
    #pragma unroll
    for (int r = 0; r < 4; ++r) a[r] = b2;
    for (int k = 0; k < HH; ++k) {
        const float w = mW2[k * HH + h];
        #pragma unroll
        for (int r = 0; r < 4; ++r) a[r] = fmaf(hsL[r][k], w, a[r]);
    }
    #pragma unroll
    for (int r = 0; r < 4; ++r) aggL[r][h] = a[r];
    __syncthreads();

    float t1[4];
    const float b3 = ub1[h];
    #pragma unroll
    for (int r = 0; r < 4; ++r) t1[r] = b3;
    for (int k = 0; k < HH; ++k) {
        const float w1 = uW1[k * HH + h];
        const float w2 = uW1[(HH + k) * HH + h];
        #pragma unroll
        for (int r = 0; r < 4; ++r) {
            t1[r] = fmaf(aggL[r][k], w1, t1[r]);
            t1[r] = fmaf(eL[r][k],  w2, t1[r]);
        }
    }
    #pragma unroll
    for (int r = 0; r < 4; ++r) t1L[r][h] = fmaxf(t1[r], 0.f);
    __syncthreads();

    float o[4];
    const float b4 = ub2[h];
    #pragma unroll
    for (int r = 0; r < 4; ++r) o[r] = b4;
    for (int k = 0; k < HH; ++k) {
        const float w = uW2[k * HH + h];
        #pragma unroll
        for (int r = 0; r < 4; ++r) o[r] = fmaf(t1L[r][k], w, o[r]);
    }
    #pragma unroll
    for (int r = 0; r < 4; ++r) out[(size_t)(i0 + r) * HH + h] = o[r];
}

extern "C" void kernel_launch(void* const* d_in, const int* in_sizes, int n_in,
                              void* d_out, int out_size, void* d_ws, size_t ws_size,
                              hipStream_t stream) {
    const float* e   = (const float*)d_in[0];
    const float* c   = (const float*)d_in[1];
    const float* mW1 = (const float*)d_in[2];
    const float* mb1 = (const float*)d_in[3];
    const float* mW2 = (const float*)d_in[4];
    const float* mb2 = (const float*)d_in[5];
    const float* uW1 = (const float*)d_in[6];
    const float* ub1 = (const float*)d_in[7];
    const float* uW2 = (const float*)d_in[8];
    const float* ub2 = (const float*)d_in[9];
    float* out = (float*)d_out;

    float* P   = (float*)d_ws;              // N*H
    float* Q   = P + NN * HH;               // N*H
    float* HSp = Q + NN * HH;               // NSLICE*N*H partials (5 MB total)

    precompute_pq<<<NN / 4, 128, 0, stream>>>(e, mW1, mb1, P, Q);
    msg_mfma<<<(NN / BI) * NSLICE, 256, 0, stream>>>(c, mW1, P, Q, HSp);
    final_mlp<<<NN / 4, 128, 0, stream>>>(e, HSp, mW2, mb2, uW1, ub1, uW2, ub2, out);
}

// Round 8
// 60.597 us; speedup vs baseline: 1.9565x; 1.0521x over previous
//
#include <hip/hip_runtime.h>

#define NN 1024
#define HH 128
#define CC 7
#define BI 8            // i per block (4 waves x 2)
#define BJ 64           // j per block
#define NCH 4           // 16-j MFMA chunks per block
#define NSLICE (NN/BJ)  // 16 j-slices -> HSp partials
#define QPAD 132        // 128 + 4: 2-way-only bank alias on q reads (free)

typedef __attribute__((ext_vector_type(8))) short bf16x8;
typedef __attribute__((ext_vector_type(4))) float f32x4;

__device__ inline unsigned short f2bf(float x) {
    union { float f; unsigned u; } v; v.f = x;
    unsigned u = v.u + 0x7FFFu + ((v.u >> 16) & 1);   // RNE
    return (unsigned short)(u >> 16);
}

// ---- Kernel A: P = e@mW1[0:H] + mb1 ; Q = e@mW1[H:2H] ----------------------
__global__ __launch_bounds__(128) void precompute_pq(
    const float* __restrict__ e, const float* __restrict__ mW1,
    const float* __restrict__ mb1, float* __restrict__ P, float* __restrict__ Q)
{
    const int h  = threadIdx.x;
    const int i0 = blockIdx.x * 2;
    __shared__ float eL[2][HH];
    #pragma unroll
    for (int r = 0; r < 2; ++r) eL[r][h] = e[(i0 + r) * HH + h];
    __syncthreads();
    float p[2], q[2];
    const float b = mb1[h];
    #pragma unroll
    for (int r = 0; r < 2; ++r) { p[r] = b; q[r] = 0.f; }
    for (int k = 0; k < HH; ++k) {
        const float w1 = mW1[k * HH + h];
        const float w2 = mW1[(HH + k) * HH + h];
        #pragma unroll
        for (int r = 0; r < 2; ++r) {
            p[r] = fmaf(eL[r][k], w1, p[r]);
            q[r] = fmaf(eL[r][k], w2, q[r]);
        }
    }
    #pragma unroll
    for (int r = 0; r < 2; ++r) {
        P[(i0 + r) * HH + h] = p[r];
        Q[(i0 + r) * HH + h] = q[r];
    }
}

// ---- Kernel B: MFMA message+reduce, stage-once, 1 barrier ------------------
// HSp[slice][i][h] = sum_{j in slice} relu( (c[i,j,:]@Cw)[h] + P[i,h] + Q[j,h] )
// MFMA 16x16x32 bf16; A-frag lane l: A[m=l&15][k=(l>>4)*8+e]; C/D lane l reg r:
// row=(l>>4)*4+r (j), col=l&15 (h)   [m89-verified]
__global__ __launch_bounds__(256, 4) void msg_mfma(
    const float* __restrict__ c, const float* __restrict__ mW1,
    const float* __restrict__ P, const float* __restrict__ Q,
    float* __restrict__ HSp)
{
    const int bid   = blockIdx.x;
    const int islab = bid >> 4;            // 0..127
    const int slice = bid & 15;            // 0..15
    const int i0    = islab * BI;
    const int j0b   = slice * BJ;
    const int t     = threadIdx.x;
    const int w     = t >> 6;              // wave 0..3
    const int l     = t & 63;
    const int g     = l >> 4;              // lane group 0..3
    const int col   = l & 15;
    const int iw0   = i0 + 2 * w;

    __shared__ float qch[BJ * QPAD];       // 33 KB

    // stage Q[j0b : j0b+64][0:128] -> qch, once
    #pragma unroll
    for (int rep = 0; rep < 8; ++rep) {
        const int f4  = t + rep * 256;     // 2048 float4s
        const int row = f4 >> 5;
        const int c4  = (f4 & 31) * 4;
        f32x4 qv = *(const f32x4*)(Q + (size_t)(j0b + row) * HH + c4);
        *(f32x4*)(qch + row * QPAD + c4) = qv;
    }

    // B fragments (Cw zero-padded K 7->32), built once
    bf16x8 bfr[8];
    #pragma unroll
    for (int ht = 0; ht < 8; ++ht) {
        bf16x8 bv = {0,0,0,0,0,0,0,0};
        if (g == 0) {
            #pragma unroll
            for (int k = 0; k < CC; ++k)
                ((short*)&bv)[k] = (short)f2bf(mW1[(2 * HH + k) * HH + 16 * ht + col]);
        }
        bfr[ht] = bv;
    }
    // P values for this wave's 2 i's
    float pv[2][8];
    #pragma unroll
    for (int ii = 0; ii < 2; ++ii)
        #pragma unroll
        for (int ht = 0; ht < 8; ++ht)
            pv[ii][ht] = P[(size_t)(iw0 + ii) * HH + 16 * ht + col];

    float acc[2][8];
    #pragma unroll
    for (int ii = 0; ii < 2; ++ii)
        #pragma unroll
        for (int ht = 0; ht < 8; ++ht) acc[ii][ht] = 0.f;

    // A fragments, double-buffered across chunks
    bf16x8 acur[2], anxt[2];
    #pragma unroll
    for (int ii = 0; ii < 2; ++ii) {
        bf16x8 av = {0,0,0,0,0,0,0,0};
        if (g == 0) {
            const float* __restrict__ cp =
                c + ((size_t)(iw0 + ii) * NN + j0b + col) * CC;
            #pragma unroll
            for (int k = 0; k < CC; ++k)
                ((short*)&av)[k] = (short)f2bf(cp[k]);
        }
        acur[ii] = av;
    }

    __syncthreads();                       // qch ready; qch is read-only after

    for (int ch = 0; ch < NCH; ++ch) {
        if (ch + 1 < NCH) {                // prefetch next chunk's A
            #pragma unroll
            for (int ii = 0; ii < 2; ++ii) {
                bf16x8 av = {0,0,0,0,0,0,0,0};
                if (g == 0) {
                    const float* __restrict__ cp =
                        c + ((size_t)(iw0 + ii) * NN + j0b + (ch + 1) * 16 + col) * CC;
                    #pragma unroll
                    for (int k = 0; k < CC; ++k)
                        ((short*)&av)[k] = (short)f2bf(cp[k]);
                }
                anxt[ii] = av;
            }
        }
        #pragma unroll
        for (int ht = 0; ht < 8; ++ht) {
            f32x4 d0 = {0.f, 0.f, 0.f, 0.f};
            f32x4 d1 = {0.f, 0.f, 0.f, 0.f};
            d0 = __builtin_amdgcn_mfma_f32_16x16x32_bf16(acur[0], bfr[ht], d0, 0, 0, 0);
            d1 = __builtin_amdgcn_mfma_f32_16x16x32_bf16(acur[1], bfr[ht], d1, 0, 0, 0);
            #pragma unroll
            for (int r = 0; r < 4; ++r) {
                const float q  = qch[(ch * 16 + g * 4 + r) * QPAD + 16 * ht + col];
                acc[0][ht] += fmaxf(d0[r] + (pv[0][ht] + q), 0.f);
                acc[1][ht] += fmaxf(d1[r] + (pv[1][ht] + q), 0.f);
            }
        }
        acur[0] = anxt[0];
        acur[1] = anxt[1];
    }

    // reduce partial j-sums across the 4 lane groups
    #pragma unroll
    for (int ii = 0; ii < 2; ++ii)
        #pragma unroll
        for (int ht = 0; ht < 8; ++ht) {
            float a = acc[ii][ht];
            a += __shfl_xor(a, 16, 64);
            a += __shfl_xor(a, 32, 64);
            acc[ii][ht] = a;
        }
    // store: group g writes ht = g and g+4
    #pragma unroll
    for (int ii = 0; ii < 2; ++ii)
        #pragma unroll
        for (int s = 0; s < 2; ++s) {
            const int ht = g + 4 * s;
            HSp[((size_t)slice * NN + iw0 + ii) * HH + 16 * ht + col] = acc[ii][ht];
        }
}

// ---- Kernel C: agg -> u -> out ---------------------------------------------
__global__ __launch_bounds__(128) void final_mlp(
    const float* __restrict__ e, const float* __restrict__ HSp,
    const float* __restrict__ mW2, const float* __restrict__ mb2,
    const float* __restrict__ uW1, const float* __restrict__ ub1,
    const float* __restrict__ uW2, const float* __restrict__ ub2,
    float* __restrict__ out)
{
    const int h  = threadIdx.x;
    const int i0 = blockIdx.x * 2;
    __shared__ float hsL[2][HH], eL[2][HH], aggL[2][HH], t1L[2][HH];
    #pragma unroll
    for (int r = 0; r < 2; ++r) {
        const size_t ih = (size_t)(i0 + r) * HH + h;
        float s = 0.f;
        #pragma unroll
        for (int sl = 0; sl < NSLICE; ++sl)
            s += HSp[(size_t)sl * NN * HH + ih];
        hsL[r][h] = s;
        eL[r][h]  = e[ih];
    }
    __syncthreads();

    float a[2];
    const float b2 = (float)NN * mb2[h];
    #pragma unroll
    for (int r = 0; r < 2; ++r) a[r] = b2;
    for (int k = 0; k < HH; ++k) {
        const float w = mW2[k * HH + h];
        #pragma unroll
        for (int r = 0; r < 2; ++r) a[r] = fmaf(hsL[r][k], w, a[r]);
    }
    #pragma unroll
    for (int r = 0; r < 2; ++r) aggL[r][h] = a[r];
    __syncthreads();

    float t1[2];
    const float b3 = ub1[h];
    #pragma unroll
    for (int r = 0; r < 2; ++r) t1[r] = b3;
    for (int k = 0; k < HH; ++k) {
        const float w1 = uW1[k * HH + h];
        const float w2 = uW1[(HH + k) * HH + h];
        #pragma unroll
        for (int r = 0; r < 2; ++r) {
            t1[r] = fmaf(aggL[r][k], w1, t1[r]);
            t1[r] = fmaf(eL[r][k],  w2, t1[r]);
        }
    }
    #pragma unroll
    for (int r = 0; r < 2; ++r) t1L[r][h] = fmaxf(t1[r], 0.f);
    __syncthreads();

    float o[2];
    const float b4 = ub2[h];
    #pragma unroll
    for (int r = 0; r < 2; ++r) o[r] = b4;
    for (int k = 0; k < HH; ++k) {
        const float w = uW2[k * HH + h];
        #pragma unroll
        for (int r = 0; r < 2; ++r) o[r] = fmaf(t1L[r][k], w, o[r]);
    }
    #pragma unroll
    for (int r = 0; r < 2; ++r) out[(size_t)(i0 + r) * HH + h] = o[r];
}

extern "C" void kernel_launch(void* const* d_in, const int* in_sizes, int n_in,
                              void* d_out, int out_size, void* d_ws, size_t ws_size,
                              hipStream_t stream) {
    const float* e   = (const float*)d_in[0];
    const float* c   = (const float*)d_in[1];
    const float* mW1 = (const float*)d_in[2];
    const float* mb1 = (const float*)d_in[3];
    const float* mW2 = (const float*)d_in[4];
    const float* mb2 = (const float*)d_in[5];
    const float* uW1 = (const float*)d_in[6];
    const float* ub1 = (const float*)d_in[7];
    const float* uW2 = (const float*)d_in[8];
    const float* ub2 = (const float*)d_in[9];
    float* out = (float*)d_out;

    float* P   = (float*)d_ws;              // N*H
    float* Q   = P + NN * HH;               // N*H
    float* HSp = Q + NN * HH;               // NSLICE*N*H partials (9 MB total)

    precompute_pq<<<NN / 2, 128, 0, stream>>>(e, mW1, mb1, P, Q);
    msg_mfma<<<(NN / BI) * NSLICE, 256, 0, stream>>>(c, mW1, P, Q, HSp);
    final_mlp<<<NN / 2, 128, 0, stream>>>(e, HSp, mW2, mb2, uW1, ub1, uW2, ub2, out);
}

// Round 9
// 50.890 us; speedup vs baseline: 2.3297x; 1.1908x over previous
//
#include <hip/hip_runtime.h>

#define NN 1024
#define HH 128
#define CC 7
#define BI 8            // i per block (4 waves x 2)
#define BJ 64           // j per block
#define NCH 4           // 16-j MFMA chunks
#define NSLICE 16       // j-slices -> HSp partials
#define QPAD 132        // 128+4: 2-way-only bank alias (free)

typedef __attribute__((ext_vector_type(8))) short bf16x8;
typedef __attribute__((ext_vector_type(4))) float f32x4;

__device__ inline unsigned short f2bf(float x) {
    union { float f; unsigned u; } v; v.f = x;
    unsigned u = v.u + 0x7FFFu + ((v.u >> 16) & 1);   // RNE
    return (unsigned short)(u >> 16);
}
// RNE-round a float bit pattern for bf16 (keep in high 16)
__device__ inline unsigned bfrnd(unsigned u) {
    return u + 0x7FFFu + ((u >> 16) & 1u);
}

// ---- Kernel A: P = e@mW1[0:H] + mb1 ; Q = e@mW1[H:2H] ----------------------
__global__ __launch_bounds__(256) void precompute_pq(
    const float* __restrict__ e, const float* __restrict__ mW1,
    const float* __restrict__ mb1, float* __restrict__ P, float* __restrict__ Q)
{
    const int t  = threadIdx.x;
    const int rr = t >> 7;
    const int h  = t & 127;
    const int i0 = blockIdx.x * 2;
    __shared__ float eL[2][HH];
    eL[rr][h] = e[(size_t)(i0 + rr) * HH + h];
    __syncthreads();
    float p = mb1[h], q = 0.f;
    for (int k = 0; k < HH; ++k) {
        const float ev = eL[rr][k];
        p = fmaf(ev, mW1[k * HH + h], p);
        q = fmaf(ev, mW1[(HH + k) * HH + h], q);
    }
    P[(size_t)(i0 + rr) * HH + h] = p;
    Q[(size_t)(i0 + rr) * HH + h] = q;
}

// ---- Kernel B: MFMA message+reduce, all-LDS main loop ----------------------
// HSp[slice][i][h] = sum_{j in slice} relu( (c[i,j,:]@Cw)[h] + P[i,h] + Q[j,h] )
// MFMA 16x16x32 bf16; A lane l: m=l&15, k=(l>>4)*8+e; C/D lane l reg r:
// row=(l>>4)*4+r (j), col=l&15 (h).  Lanes 16-63's A values are garbage but
// multiply B rows k>=8 which are zero -> contribute nothing.
__global__ __launch_bounds__(256, 3) void msg_mfma(
    const float* __restrict__ c, const float* __restrict__ mW1,
    const float* __restrict__ P, const float* __restrict__ Q,
    float* __restrict__ HSp)
{
    const int bid   = blockIdx.x;
    const int islab = bid >> 4;            // 0..127
    const int slice = bid & 15;            // 0..15
    const int i0    = islab * BI;
    const int j0b   = slice * BJ;
    const int t     = threadIdx.x;
    const int w     = t >> 6;              // wave 0..3
    const int l     = t & 63;
    const int g     = l >> 4;              // lane group 0..3
    const int col   = l & 15;
    const int iw0   = i0 + 2 * w;

    __shared__ float qch[BJ * QPAD];       // 33.8 KB
    __shared__ uint4 abuf[BI * BJ];        // 8 KB: packed bf16x8 A-rows

    // ---- stage Q[j0b:j0b+64][0:128] -> qch (coalesced f32x4)
    #pragma unroll
    for (int rep = 0; rep < 8; ++rep) {
        const int f4  = t + rep * 256;
        const int row = f4 >> 5;
        const int c4  = (f4 & 31) * 4;
        *(f32x4*)(qch + row * QPAD + c4) =
            *(const f32x4*)(Q + (size_t)(j0b + row) * HH + c4);
    }
    // ---- stage c -> abuf as packed bf16x8 rows (coalesced, all lanes)
    #pragma unroll
    for (int rep = 0; rep < 2; ++rep) {
        const int rr = t + rep * 256;      // 0..511
        const int ii = rr >> 6;
        const int jj = rr & 63;
        const unsigned* __restrict__ cp = (const unsigned*)
            (c + ((size_t)(i0 + ii) * NN + j0b + jj) * CC);
        unsigned d0 = bfrnd(cp[0]), d1 = bfrnd(cp[1]), d2 = bfrnd(cp[2]);
        unsigned d3 = bfrnd(cp[3]), d4 = bfrnd(cp[4]), d5 = bfrnd(cp[5]);
        unsigned d6 = bfrnd(cp[6]);
        uint4 pk;
        pk.x = __builtin_amdgcn_perm(d1, d0, 0x07060302u);  // [d0.hi, d1.hi]
        pk.y = __builtin_amdgcn_perm(d3, d2, 0x07060302u);
        pk.z = __builtin_amdgcn_perm(d5, d4, 0x07060302u);
        pk.w = d6 >> 16;                                    // k=7 pad zero
        abuf[rr] = pk;
    }

    // ---- B fragments (Cw), zeros outside k<7 / g==0 — REQUIRED zeros
    bf16x8 bfr[8];
    #pragma unroll
    for (int ht = 0; ht < 8; ++ht) {
        bf16x8 bv = {0,0,0,0,0,0,0,0};
        if (g == 0) {
            #pragma unroll
            for (int k = 0; k < CC; ++k)
                ((short*)&bv)[k] = (short)f2bf(mW1[(2 * HH + k) * HH + 16 * ht + col]);
        }
        bfr[ht] = bv;
    }
    // ---- P values for this wave's 2 i's
    float pv[2][8];
    #pragma unroll
    for (int ii = 0; ii < 2; ++ii)
        #pragma unroll
        for (int ht = 0; ht < 8; ++ht)
            pv[ii][ht] = P[(size_t)(iw0 + ii) * HH + 16 * ht + col];

    float acc[2][8];
    #pragma unroll
    for (int ii = 0; ii < 2; ++ii)
        #pragma unroll
        for (int ht = 0; ht < 8; ++ht) acc[ii][ht] = 0.f;

    __syncthreads();                       // staging done; LDS read-only after

    for (int ch = 0; ch < NCH; ++ch) {
        const uint4 a0 = abuf[(2 * w + 0) * 64 + ch * 16 + col];
        const uint4 a1 = abuf[(2 * w + 1) * 64 + ch * 16 + col];
        const bf16x8 af0 = __builtin_bit_cast(bf16x8, a0);
        const bf16x8 af1 = __builtin_bit_cast(bf16x8, a1);
        const int qbase = (ch * 16 + g * 4) * QPAD + col;
        #pragma unroll
        for (int ht = 0; ht < 8; ++ht) {
            f32x4 d0, d1;
            #pragma unroll
            for (int r = 0; r < 4; ++r) {
                const float q = qch[qbase + r * QPAD + 16 * ht];
                d0[r] = pv[0][ht] + q;     // C-init: P + Q
                d1[r] = pv[1][ht] + q;
            }
            d0 = __builtin_amdgcn_mfma_f32_16x16x32_bf16(af0, bfr[ht], d0, 0, 0, 0);
            d1 = __builtin_amdgcn_mfma_f32_16x16x32_bf16(af1, bfr[ht], d1, 0, 0, 0);
            #pragma unroll
            for (int r = 0; r < 4; ++r) {
                acc[0][ht] += fmaxf(d0[r], 0.f);
                acc[1][ht] += fmaxf(d1[r], 0.f);
            }
        }
    }

    // reduce partial j-sums across the 4 lane groups
    #pragma unroll
    for (int ii = 0; ii < 2; ++ii)
        #pragma unroll
        for (int ht = 0; ht < 8; ++ht) {
            float a = acc[ii][ht];
            a += __shfl_xor(a, 16, 64);
            a += __shfl_xor(a, 32, 64);
            acc[ii][ht] = a;
        }
    // store: group g writes ht = g and g+4
    #pragma unroll
    for (int ii = 0; ii < 2; ++ii)
        #pragma unroll
        for (int s = 0; s < 2; ++s) {
            const int ht = g + 4 * s;
            HSp[((size_t)slice * NN + iw0 + ii) * HH + 16 * ht + col] = acc[ii][ht];
        }
}

// ---- Kernel C: agg -> u -> out, k-split across thread halves ---------------
__global__ __launch_bounds__(256) void final_mlp(
    const float* __restrict__ e, const float* __restrict__ HSp,
    const float* __restrict__ mW2, const float* __restrict__ mb2,
    const float* __restrict__ uW1, const float* __restrict__ ub1,
    const float* __restrict__ uW2, const float* __restrict__ ub2,
    float* __restrict__ out)
{
    const int t  = threadIdx.x;
    const int s  = t >> 7;                 // k-half / row selector
    const int h  = t & 127;
    const int i0 = blockIdx.x * 2;
    __shared__ float hsL[2][HH], eL[2][HH], aggL[2][HH], t1L[2][HH], part[2][2][HH];

    {   // entry: thread (s,h) fills row r=s
        const size_t ih = (size_t)(i0 + s) * HH + h;
        float sum = 0.f;
        #pragma unroll
        for (int sl = 0; sl < NSLICE; ++sl)
            sum += HSp[(size_t)sl * NN * HH + ih];
        hsL[s][h] = sum;
        eL[s][h]  = e[ih];
    }
    __syncthreads();

    {   // stage 1: agg = HS@mW2 + N*mb2   (k-half split)
        float a0 = 0.f, a1 = 0.f;
        const int k0 = 64 * s;
        for (int k = k0; k < k0 + 64; ++k) {
            const float wv = mW2[k * HH + h];
            a0 = fmaf(hsL[0][k], wv, a0);
            a1 = fmaf(hsL[1][k], wv, a1);
        }
        part[s][0][h] = a0; part[s][1][h] = a1;
    }
    __syncthreads();
    aggL[s][h] = part[0][s][h] + part[1][s][h] + (float)NN * mb2[h];
    __syncthreads();

    {   // stage 2: t1 = relu([agg,e]@uW1 + ub1)  (s=0: agg-part, s=1: e-part)
        float b0 = 0.f, b1 = 0.f;
        const float* __restrict__ src   = (s == 0) ? &aggL[0][0] : &eL[0][0];
        const float* __restrict__ wbase = uW1 + (size_t)s * HH * HH;
        for (int k = 0; k < HH; ++k) {
            const float wv = wbase[k * HH + h];
            b0 = fmaf(src[k],      wv, b0);
            b1 = fmaf(src[HH + k], wv, b1);
        }
        part[s][0][h] = b0; part[s][1][h] = b1;
    }
    __syncthreads();
    t1L[s][h] = fmaxf(part[0][s][h] + part[1][s][h] + ub1[h], 0.f);
    __syncthreads();

    {   // stage 3: out = t1@uW2 + ub2   (k-half split)
        float c0 = 0.f, c1 = 0.f;
        const int k0 = 64 * s;
        for (int k = k0; k < k0 + 64; ++k) {
            const float wv = uW2[k * HH + h];
            c0 = fmaf(t1L[0][k], wv, c0);
            c1 = fmaf(t1L[1][k], wv, c1);
        }
        part[s][0][h] = c0; part[s][1][h] = c1;
    }
    __syncthreads();
    out[(size_t)(i0 + s) * HH + h] = part[0][s][h] + part[1][s][h] + ub2[h];
}

extern "C" void kernel_launch(void* const* d_in, const int* in_sizes, int n_in,
                              void* d_out, int out_size, void* d_ws, size_t ws_size,
                              hipStream_t stream) {
    const float* e   = (const float*)d_in[0];
    const float* c   = (const float*)d_in[1];
    const float* mW1 = (const float*)d_in[2];
    const float* mb1 = (const float*)d_in[3];
    const float* mW2 = (const float*)d_in[4];
    const float* mb2 = (const float*)d_in[5];
    const float* uW1 = (const float*)d_in[6];
    const float* ub1 = (const float*)d_in[7];
    const float* uW2 = (const float*)d_in[8];
    const float* ub2 = (const float*)d_in[9];
    float* out = (float*)d_out;

    float* P   = (float*)d_ws;              // N*H
    float* Q   = P + NN * HH;               // N*H
    float* HSp = Q + NN * HH;               // NSLICE*N*H partials

    precompute_pq<<<NN / 2, 256, 0, stream>>>(e, mW1, mb1, P, Q);
    msg_mfma<<<(NN / BI) * NSLICE, 256, 0, stream>>>(c, mW1, P, Q, HSp);
    final_mlp<<<NN / 2, 256, 0, stream>>>(e, HSp, mW2, mb2, uW1, ub1, uW2, ub2, out);
}